// Round 1
// baseline (453.638 us; speedup 1.0000x reference)
//
#include <hip/hip_runtime.h>

#define N_NODES 50000
#define N_EDGES 800000
#define CH 128  // feature width for both GEMM stages (layer2/3 fused)

// ---------------- CSR build ----------------

__global__ void count_kernel(const int* __restrict__ ei, int* __restrict__ counts) {
    int e = blockIdx.x * blockDim.x + threadIdx.x;
    if (e < N_EDGES) {
        int dst = ei[N_EDGES + e];
        atomicAdd(&counts[dst], 1);
    }
}

__global__ void dinv_kernel(const int* __restrict__ counts, float* __restrict__ dinv) {
    int i = blockIdx.x * blockDim.x + threadIdx.x;
    if (i < N_NODES) dinv[i] = rsqrtf((float)(counts[i] + 1));  // +1 self-loop; always > 0
}

__global__ __launch_bounds__(1024) void scan_kernel(const int* __restrict__ counts,
                                                    int* __restrict__ row_ptr) {
    __shared__ int sums[1024];
    const int n = N_NODES;
    int tid = threadIdx.x;
    int chunk = (n + 1023) / 1024;  // 49
    int start = tid * chunk; if (start > n) start = n;
    int end = start + chunk; if (end > n) end = n;
    int s = 0;
    for (int i = start; i < end; ++i) s += counts[i];
    sums[tid] = s;
    __syncthreads();
    int val = s;
    for (int off = 1; off < 1024; off <<= 1) {
        int t = (tid >= off) ? sums[tid - off] : 0;
        __syncthreads();
        sums[tid] += t;
        __syncthreads();
    }
    int run = sums[tid] - val;  // exclusive prefix
    for (int i = start; i < end; ++i) { row_ptr[i] = run; run += counts[i]; }
    if (tid == 1023) row_ptr[n] = sums[1023];
}

__global__ void cursor_kernel(const int* __restrict__ row_ptr, int* __restrict__ cursor) {
    int i = blockIdx.x * blockDim.x + threadIdx.x;
    if (i < N_NODES) cursor[i] = row_ptr[i];
}

__global__ void scatter_kernel(const int* __restrict__ ei, int* __restrict__ cursor,
                               int* __restrict__ sorted_src) {
    int e = blockIdx.x * blockDim.x + threadIdx.x;
    if (e < N_EDGES) {
        int src = ei[e];
        int dst = ei[N_EDGES + e];
        int pos = atomicAdd(&cursor[dst], 1);
        sorted_src[pos] = src;
    }
}

// ---------------- weight fusion (W2|W3, b2|b3) ----------------

__global__ void fuse_w_kernel(const float* __restrict__ W2, const float* __restrict__ W3,
                              const float* __restrict__ b2, const float* __restrict__ b3,
                              float* __restrict__ W23, float* __restrict__ b23) {
    int i = blockIdx.x * blockDim.x + threadIdx.x;
    if (i < 128 * 128) {
        int c = i >> 7, k = i & 127;
        W23[i] = (k < 64) ? W2[c * 64 + k] : W3[c * 64 + (k - 64)];
    } else if (i < 128 * 128 + 128) {
        int k = i - 128 * 128;
        b23[k] = (k < 64) ? b2[k] : b3[k - 64];
    }
}

// ---------------- GEMM: out[n][k] = dinv[n] * sum_c in[n][c] * W[c][k] ----------------
// 16 rows/block, 256 threads: k = tid&127, half = tid>>7; each thread does 8 rows.

#define GR 16
__global__ __launch_bounds__(256) void gemm_scaled(const float* __restrict__ in,
                                                   const float* __restrict__ W,
                                                   const float* __restrict__ dinv,
                                                   float* __restrict__ out) {
    __shared__ float xs[GR][CH];
    int k = threadIdx.x & 127;
    int half = threadIdx.x >> 7;  // wave-uniform (waves 0,1 -> 0; waves 2,3 -> 1)
    int row0 = blockIdx.x * GR;
    for (int i = threadIdx.x; i < GR * CH; i += 256) {
        int r = i >> 7, c = i & 127;
        int gr = row0 + r;
        xs[r][c] = (gr < N_NODES) ? in[gr * CH + c] : 0.0f;
    }
    __syncthreads();
    float acc[8] = {0.f, 0.f, 0.f, 0.f, 0.f, 0.f, 0.f, 0.f};
    for (int c = 0; c < CH; ++c) {
        float w = W[c * CH + k];
#pragma unroll
        for (int j = 0; j < 8; ++j)
            acc[j] += xs[half + 2 * j][c] * w;  // LDS broadcast (wave-uniform addr)
    }
#pragma unroll
    for (int j = 0; j < 8; ++j) {
        int r = row0 + half + 2 * j;
        if (r < N_NODES) out[r * CH + k] = acc[j] * dinv[r];
    }
}

// ---------------- aggregation: out[n] = relu(dinv[n]*(g[n] + sum_{e in CSR[n]} g[src]) + b) ----
// g is already pre-scaled by dinv[src]. One block of 128 threads per node.

template <bool SPLIT>
__global__ __launch_bounds__(128) void aggregate_kernel(const float* __restrict__ g,
                                                        const float* __restrict__ dinv,
                                                        const int* __restrict__ row_ptr,
                                                        const int* __restrict__ srcs,
                                                        const float* __restrict__ bias,
                                                        float* __restrict__ out) {
    int n = blockIdx.x;
    int ch = threadIdx.x;
    int beg = row_ptr[n], end = row_ptr[n + 1];
    float acc = g[n * CH + ch];  // self-loop term (g already has one dinv[n] factor)
    int e = beg;
    for (; e + 1 < end; e += 2) {  // 2-way unroll: independent gathers in flight
        int s0 = srcs[e], s1 = srcs[e + 1];
        float v0 = g[s0 * CH + ch];
        float v1 = g[s1 * CH + ch];
        acc += v0;
        acc += v1;
    }
    if (e < end) acc += g[srcs[e] * CH + ch];
    float o = fmaxf(dinv[n] * acc + bias[ch], 0.0f);
    if (!SPLIT) {
        out[n * CH + ch] = o;
    } else {
        if (ch < 64) out[n * 64 + ch] = o;                        // x1
        else out[N_NODES * 64 + n * 64 + (ch - 64)] = o;          // x2
    }
}

// ---------------- launch ----------------

extern "C" void kernel_launch(void* const* d_in, const int* in_sizes, int n_in,
                              void* d_out, int out_size, void* d_ws, size_t ws_size,
                              hipStream_t stream) {
    const float* x  = (const float*)d_in[0];
    const int*   ei = (const int*)d_in[1];   // [2, E] int32 (jax x64 disabled)
    const float* W1 = (const float*)d_in[2];
    const float* b1 = (const float*)d_in[3];
    const float* W2 = (const float*)d_in[4];
    const float* b2 = (const float*)d_in[5];
    const float* W3 = (const float*)d_in[6];
    const float* b3 = (const float*)d_in[7];
    float* out = (float*)d_out;

    char* w = (char*)d_ws;
    int*   counts     = (int*)(w + 0);          // 200000 B (doubles as cursor)
    int*   row_ptr    = (int*)(w + 204800);     // 200004 B
    float* dinv       = (float*)(w + 409600);   // 200000 B
    int*   sorted_src = (int*)(w + 614400);     // 3.2 MB
    float* W23        = (float*)(w + 3814400);  // 64 KiB
    float* b23        = (float*)(w + 3879936);  // 512 B
    float* g1         = (float*)(w + 4194304);  // 25.6 MB (reused as g2)
    float* hidden     = (float*)(w + 33554432); // 25.6 MB

    // CSR build + dinv
    hipMemsetAsync(counts, 0, N_NODES * sizeof(int), stream);
    count_kernel<<<(N_EDGES + 255) / 256, 256, 0, stream>>>(ei, counts);
    dinv_kernel<<<(N_NODES + 255) / 256, 256, 0, stream>>>(counts, dinv);
    scan_kernel<<<1, 1024, 0, stream>>>(counts, row_ptr);
    cursor_kernel<<<(N_NODES + 255) / 256, 256, 0, stream>>>(row_ptr, counts);
    scatter_kernel<<<(N_EDGES + 255) / 256, 256, 0, stream>>>(ei, counts, sorted_src);

    // fused layer-2/3 weights
    fuse_w_kernel<<<(128 * 128 + 128 + 255) / 256, 256, 0, stream>>>(W2, W3, b2, b3, W23, b23);

    const int gemm_blocks = (N_NODES + GR - 1) / GR;

    // layer 1: g1 = dinv * (x @ W1); hidden = relu(dinv*(g1_self + sum g1[src]) + b1)
    gemm_scaled<<<gemm_blocks, 256, 0, stream>>>(x, W1, dinv, g1);
    aggregate_kernel<false><<<N_NODES, 128, 0, stream>>>(g1, dinv, row_ptr, sorted_src, b1, hidden);

    // layers 2+3 fused: g2 = dinv * (hidden @ [W2|W3]); out = relu(... + [b2|b3]) split-written
    gemm_scaled<<<gemm_blocks, 256, 0, stream>>>(hidden, W23, dinv, g1);
    aggregate_kernel<true><<<N_NODES, 128, 0, stream>>>(g1, dinv, row_ptr, sorted_src, b23, out);
}

// Round 2
// 376.558 us; speedup vs baseline: 1.2047x; 1.2047x over previous
//
#include <hip/hip_runtime.h>

#define N_NODES 50000
#define N_EDGES 800000
#define CH 128          // feature width for both GEMM stages (layer2/3 fused)
#define SCAN_BLKS 98    // ceil(50000 / 512)

// ---------------- CSR build ----------------

__global__ void count_kernel(const int* __restrict__ ei, int* __restrict__ counts) {
    int e = blockIdx.x * blockDim.x + threadIdx.x;
    if (e < N_EDGES) {
        int dst = ei[N_EDGES + e];
        atomicAdd(&counts[dst], 1);
    }
}

// 98 blocks x 256 thr; each block scans 512 counts (2/thread), writes local
// exclusive scan into row_ptr, block total into bsum. Also computes dinv.
__global__ __launch_bounds__(256) void scan_block_kernel(const int* __restrict__ counts,
                                                         int* __restrict__ row_ptr,
                                                         float* __restrict__ dinv,
                                                         int* __restrict__ bsum) {
    __shared__ int s[256];
    int tid = threadIdx.x;
    int base = blockIdx.x * 512;
    int i0 = base + 2 * tid, i1 = i0 + 1;
    int v0 = (i0 < N_NODES) ? counts[i0] : 0;
    int v1 = (i1 < N_NODES) ? counts[i1] : 0;
    if (i0 < N_NODES) dinv[i0] = rsqrtf((float)(v0 + 1));  // +1 self-loop
    if (i1 < N_NODES) dinv[i1] = rsqrtf((float)(v1 + 1));
    int t = v0 + v1;
    s[tid] = t;
    __syncthreads();
    for (int off = 1; off < 256; off <<= 1) {
        int tmp = (tid >= off) ? s[tid - off] : 0;
        __syncthreads();
        s[tid] += tmp;
        __syncthreads();
    }
    int pre = s[tid] - t;  // exclusive prefix within block
    if (i0 < N_NODES) row_ptr[i0] = pre;
    if (i1 < N_NODES) row_ptr[i1] = pre + v0;
    if (tid == 255) bsum[blockIdx.x] = s[255];
}

// single small block: exclusive scan of the 98 block sums; writes row_ptr[N].
__global__ __launch_bounds__(128) void scan_tops_kernel(const int* __restrict__ bsum,
                                                        int* __restrict__ boff,
                                                        int* __restrict__ row_ptr) {
    __shared__ int s[128];
    int tid = threadIdx.x;
    int v = (tid < SCAN_BLKS) ? bsum[tid] : 0;
    s[tid] = v;
    __syncthreads();
    for (int off = 1; off < 128; off <<= 1) {
        int tmp = (tid >= off) ? s[tid - off] : 0;
        __syncthreads();
        s[tid] += tmp;
        __syncthreads();
    }
    if (tid < SCAN_BLKS) boff[tid] = s[tid] - v;
    if (tid == 127) row_ptr[N_NODES] = s[127];
}

// add block offsets; also initialize scatter cursor (reuses counts buffer).
__global__ __launch_bounds__(256) void scan_add_kernel(int* __restrict__ row_ptr,
                                                       const int* __restrict__ boff,
                                                       int* __restrict__ cursor) {
    int base = blockIdx.x * 512;
    int off = boff[blockIdx.x];
    for (int i = base + threadIdx.x; i < base + 512; i += 256) {
        if (i < N_NODES) {
            int v = row_ptr[i] + off;
            row_ptr[i] = v;
            cursor[i] = v;
        }
    }
}

__global__ void scatter_kernel(const int* __restrict__ ei, int* __restrict__ cursor,
                               int* __restrict__ sorted_src) {
    int e = blockIdx.x * blockDim.x + threadIdx.x;
    if (e < N_EDGES) {
        int src = ei[e];
        int dst = ei[N_EDGES + e];
        int pos = atomicAdd(&cursor[dst], 1);
        sorted_src[pos] = src;
    }
}

// ---------------- weight fusion (W2|W3, b2|b3) ----------------

__global__ void fuse_w_kernel(const float* __restrict__ W2, const float* __restrict__ W3,
                              const float* __restrict__ b2, const float* __restrict__ b3,
                              float* __restrict__ W23, float* __restrict__ b23) {
    int i = blockIdx.x * blockDim.x + threadIdx.x;
    if (i < 128 * 128) {
        int c = i >> 7, k = i & 127;
        W23[i] = (k < 64) ? W2[c * 64 + k] : W3[c * 64 + (k - 64)];
    } else if (i < 128 * 128 + 128) {
        int k = i - 128 * 128;
        b23[k] = (k < 64) ? b2[k] : b3[k - 64];
    }
}

// ---------------- GEMM: out[n][k] = dinv[n] * sum_c in[n][c] * W[c][k] ----------------
// 16 rows/block, 256 threads: k = tid&127, half = tid>>7; each thread does 8 rows.
// Inner loop c-quad unrolled: one ds_read_b128 feeds 4 FMAs.

#define GR 16
__global__ __launch_bounds__(256) void gemm_scaled(const float* __restrict__ in,
                                                   const float* __restrict__ W,
                                                   const float* __restrict__ dinv,
                                                   float* __restrict__ out) {
    __shared__ float xs[GR][CH];  // 8 KiB
    int k = threadIdx.x & 127;
    int half = threadIdx.x >> 7;  // wave-uniform
    int row0 = blockIdx.x * GR;
    // stage 16 rows with float4 loads (512 float4, 2/thread)
    for (int i = threadIdx.x; i < GR * CH / 4; i += 256) {
        int r = i >> 5;
        int cq = i & 31;
        int gr = row0 + r;
        float4 v = make_float4(0.f, 0.f, 0.f, 0.f);
        if (gr < N_NODES) v = ((const float4*)in)[gr * 32 + cq];
        *(float4*)&xs[r][cq * 4] = v;
    }
    __syncthreads();
    float acc[8] = {0.f, 0.f, 0.f, 0.f, 0.f, 0.f, 0.f, 0.f};
    for (int c = 0; c < CH; c += 4) {
        float w0 = W[(c + 0) * CH + k];
        float w1 = W[(c + 1) * CH + k];
        float w2 = W[(c + 2) * CH + k];
        float w3 = W[(c + 3) * CH + k];
#pragma unroll
        for (int j = 0; j < 8; ++j) {
            float4 xv = *(const float4*)&xs[half + 2 * j][c];  // broadcast b128
            acc[j] += xv.x * w0;
            acc[j] += xv.y * w1;
            acc[j] += xv.z * w2;
            acc[j] += xv.w * w3;
        }
    }
#pragma unroll
    for (int j = 0; j < 8; ++j) {
        int r = row0 + half + 2 * j;
        if (r < N_NODES) out[r * CH + k] = acc[j] * dinv[r];
    }
}

// ---------------- aggregation ----------------
// out[n] = relu(dinv[n]*(g[n] + sum_{e in CSR[n]} g[src[e]]) + b), g pre-scaled by dinv[src].
// 256 threads = 8 half-waves; each half-wave (32 lanes x float4) owns one node.

template <bool SPLIT>
__global__ __launch_bounds__(256) void aggregate_kernel(const float* __restrict__ g,
                                                        const float* __restrict__ dinv,
                                                        const int* __restrict__ row_ptr,
                                                        const int* __restrict__ srcs,
                                                        const float* __restrict__ bias,
                                                        float* __restrict__ out) {
    int sub = threadIdx.x >> 5;               // 0..7
    int n = blockIdx.x * 8 + sub;
    if (n >= N_NODES) return;
    int cq = threadIdx.x & 31;                // float4 index within row
    const float4* grow = (const float4*)g;
    float4 acc = grow[n * 32 + cq];           // self-loop term
    float4 acc2 = make_float4(0.f, 0.f, 0.f, 0.f);
    int e = row_ptr[n], end = row_ptr[n + 1];
    for (; e + 1 < end; e += 2) {
        int s0 = srcs[e], s1 = srcs[e + 1];
        float4 v0 = grow[s0 * 32 + cq];
        float4 v1 = grow[s1 * 32 + cq];
        acc.x += v0.x; acc.y += v0.y; acc.z += v0.z; acc.w += v0.w;
        acc2.x += v1.x; acc2.y += v1.y; acc2.z += v1.z; acc2.w += v1.w;
    }
    if (e < end) {
        float4 v = grow[srcs[e] * 32 + cq];
        acc.x += v.x; acc.y += v.y; acc.z += v.z; acc.w += v.w;
    }
    acc.x += acc2.x; acc.y += acc2.y; acc.z += acc2.z; acc.w += acc2.w;
    float d = dinv[n];
    float4 bv = ((const float4*)bias)[cq];
    float4 o;
    o.x = fmaxf(d * acc.x + bv.x, 0.f);
    o.y = fmaxf(d * acc.y + bv.y, 0.f);
    o.z = fmaxf(d * acc.z + bv.z, 0.f);
    o.w = fmaxf(d * acc.w + bv.w, 0.f);
    if (!SPLIT) {
        ((float4*)out)[n * 32 + cq] = o;
    } else {
        int ch = cq * 4;
        if (ch < 64) ((float4*)out)[n * 16 + cq] = o;                       // x1
        else ((float4*)(out + N_NODES * 64))[n * 16 + (cq - 16)] = o;       // x2
    }
}

// ---------------- launch ----------------

extern "C" void kernel_launch(void* const* d_in, const int* in_sizes, int n_in,
                              void* d_out, int out_size, void* d_ws, size_t ws_size,
                              hipStream_t stream) {
    const float* x  = (const float*)d_in[0];
    const int*   ei = (const int*)d_in[1];   // [2, E] int32
    const float* W1 = (const float*)d_in[2];
    const float* b1 = (const float*)d_in[3];
    const float* W2 = (const float*)d_in[4];
    const float* b2 = (const float*)d_in[5];
    const float* W3 = (const float*)d_in[6];
    const float* b3 = (const float*)d_in[7];
    float* out = (float*)d_out;

    char* w = (char*)d_ws;
    int*   counts     = (int*)(w + 0);          // 200000 B (reused as cursor)
    int*   row_ptr    = (int*)(w + 204800);     // 200004 B
    float* dinv       = (float*)(w + 409600);   // 200000 B
    int*   sorted_src = (int*)(w + 614400);     // 3.2 MB
    float* W23        = (float*)(w + 3814400);  // 64 KiB
    float* b23        = (float*)(w + 3879936);  // 512 B
    int*   bsum       = (int*)(w + 3880448);    // 392 B
    int*   boff       = (int*)(w + 3880960);    // 392 B
    float* g1         = (float*)(w + 4194304);  // 25.6 MB (reused for layer 2/3)
    float* hidden     = (float*)(w + 33554432); // 25.6 MB

    // CSR build + dinv (hierarchical scan, ~3 tiny kernels)
    hipMemsetAsync(counts, 0, N_NODES * sizeof(int), stream);
    count_kernel<<<(N_EDGES + 255) / 256, 256, 0, stream>>>(ei, counts);
    scan_block_kernel<<<SCAN_BLKS, 256, 0, stream>>>(counts, row_ptr, dinv, bsum);
    scan_tops_kernel<<<1, 128, 0, stream>>>(bsum, boff, row_ptr);
    scan_add_kernel<<<SCAN_BLKS, 256, 0, stream>>>(row_ptr, boff, counts);
    scatter_kernel<<<(N_EDGES + 255) / 256, 256, 0, stream>>>(ei, counts, sorted_src);

    // fused layer-2/3 weights
    fuse_w_kernel<<<(128 * 128 + 128 + 255) / 256, 256, 0, stream>>>(W2, W3, b2, b3, W23, b23);

    const int gemm_blocks = (N_NODES + GR - 1) / GR;   // 3125
    const int agg_blocks = (N_NODES + 7) / 8;          // 6250

    // layer 1
    gemm_scaled<<<gemm_blocks, 256, 0, stream>>>(x, W1, dinv, g1);
    aggregate_kernel<false><<<agg_blocks, 256, 0, stream>>>(g1, dinv, row_ptr, sorted_src, b1, hidden);

    // layers 2+3 fused
    gemm_scaled<<<gemm_blocks, 256, 0, stream>>>(hidden, W23, dinv, g1);
    aggregate_kernel<true><<<agg_blocks, 256, 0, stream>>>(g1, dinv, row_ptr, sorted_src, b23, out);
}

// Round 3
// 286.826 us; speedup vs baseline: 1.5816x; 1.3128x over previous
//
#include <hip/hip_runtime.h>

#define N_NODES 50000
#define N_EDGES 800000
#define CH 128          // feature width for both GEMM stages (layer2/3 fused)
#define SCAN_BLKS 98    // ceil(50000 / 512)
#define WT_PAD 136      // Wt LDS row stride in shorts (272 B: 16B-aligned, 2-way-free banks)

typedef __attribute__((ext_vector_type(8))) short short8;   // 8 bf16 = one MFMA A/B frag
typedef __attribute__((ext_vector_type(4))) float floatx4;  // MFMA C/D frag

__device__ __forceinline__ short f2bf(float f) {  // RNE float->bf16
    union { float f; unsigned u; } v; v.f = f;
    unsigned r = v.u + 0x7fff + ((v.u >> 16) & 1);
    return (short)(r >> 16);
}
__device__ __forceinline__ float bflo(unsigned u) {  // low bf16 of packed pair -> f32
    union { unsigned u; float f; } v; v.u = u << 16; return v.f;
}
__device__ __forceinline__ float bfhi(unsigned u) {
    union { unsigned u; float f; } v; v.u = u & 0xffff0000u; return v.f;
}

// ---------------- CSR build ----------------

__global__ void count_kernel(const int* __restrict__ ei, int* __restrict__ counts) {
    int e = blockIdx.x * blockDim.x + threadIdx.x;
    if (e < N_EDGES) atomicAdd(&counts[ei[N_EDGES + e]], 1);
}

__global__ __launch_bounds__(256) void scan_block_kernel(const int* __restrict__ counts,
                                                         int* __restrict__ row_ptr,
                                                         float* __restrict__ dinv,
                                                         int* __restrict__ bsum) {
    __shared__ int s[256];
    int tid = threadIdx.x;
    int base = blockIdx.x * 512;
    int i0 = base + 2 * tid, i1 = i0 + 1;
    int v0 = (i0 < N_NODES) ? counts[i0] : 0;
    int v1 = (i1 < N_NODES) ? counts[i1] : 0;
    if (i0 < N_NODES) dinv[i0] = rsqrtf((float)(v0 + 1));  // +1 self-loop
    if (i1 < N_NODES) dinv[i1] = rsqrtf((float)(v1 + 1));
    int t = v0 + v1;
    s[tid] = t;
    __syncthreads();
    for (int off = 1; off < 256; off <<= 1) {
        int tmp = (tid >= off) ? s[tid - off] : 0;
        __syncthreads();
        s[tid] += tmp;
        __syncthreads();
    }
    int pre = s[tid] - t;
    if (i0 < N_NODES) row_ptr[i0] = pre;
    if (i1 < N_NODES) row_ptr[i1] = pre + v0;
    if (tid == 255) bsum[blockIdx.x] = s[255];
}

__global__ __launch_bounds__(128) void scan_tops_kernel(const int* __restrict__ bsum,
                                                        int* __restrict__ boff,
                                                        int* __restrict__ row_ptr) {
    __shared__ int s[128];
    int tid = threadIdx.x;
    int v = (tid < SCAN_BLKS) ? bsum[tid] : 0;
    s[tid] = v;
    __syncthreads();
    for (int off = 1; off < 128; off <<= 1) {
        int tmp = (tid >= off) ? s[tid - off] : 0;
        __syncthreads();
        s[tid] += tmp;
        __syncthreads();
    }
    if (tid < SCAN_BLKS) boff[tid] = s[tid] - v;
    if (tid == 127) row_ptr[N_NODES] = s[127];
}

__global__ __launch_bounds__(256) void scan_add_kernel(int* __restrict__ row_ptr,
                                                       const int* __restrict__ boff,
                                                       int* __restrict__ cursor) {
    int base = blockIdx.x * 512;
    int off = boff[blockIdx.x];
    for (int i = base + threadIdx.x; i < base + 512; i += 256) {
        if (i < N_NODES) {
            int v = row_ptr[i] + off;
            row_ptr[i] = v;
            cursor[i] = v;
        }
    }
}

__global__ void scatter_kernel(const int* __restrict__ ei, int* __restrict__ cursor,
                               int* __restrict__ sorted_src) {
    int e = blockIdx.x * blockDim.x + threadIdx.x;
    if (e < N_EDGES) {
        int src = ei[e];
        int dst = ei[N_EDGES + e];
        int pos = atomicAdd(&cursor[dst], 1);
        sorted_src[pos] = src;
    }
}

// ---------------- weight prep: transpose to [n][k] + bf16 + fuse W2|W3 ----------------

__global__ void prep_weights(const float* __restrict__ W1, const float* __restrict__ W2,
                             const float* __restrict__ W3, const float* __restrict__ b2,
                             const float* __restrict__ b3, unsigned short* __restrict__ Wt1,
                             unsigned short* __restrict__ Wt23, float* __restrict__ b23) {
    int i = blockIdx.x * blockDim.x + threadIdx.x;
    if (i < 128 * 128) {
        int n = i >> 7, k = i & 127;
        Wt1[i] = (unsigned short)f2bf(W1[k * 128 + n]);
        float w = (n < 64) ? W2[k * 64 + n] : W3[k * 64 + (n - 64)];
        Wt23[i] = (unsigned short)f2bf(w);
    } else if (i < 128 * 128 + 128) {
        int k2 = i - 128 * 128;
        b23[k2] = (k2 < 64) ? b2[k2] : b3[k2 - 64];
    }
}

// ---------------- MFMA GEMM: g[n][ch] = bf16( dinv[n] * sum_c A[n][c]*W[c][ch] ) -------
// 256 thr = 4 waves; block covers 64 rows (16/wave) x 128 cols.
// Wt [n][k] bf16 staged to LDS (pad 136); B-frag = one ds_read_b128, 1:1 with MFMA.
// A-frag loaded direct from global (fp32 path converts inline).
// Epilogue: D-frags -> LDS transpose (reusing Wt space) -> coalesced bf16 stores.

template <bool A_BF16>
__global__ __launch_bounds__(256) void gemm_mfma(const void* __restrict__ Ain,
                                                 const unsigned short* __restrict__ Wt,
                                                 const float* __restrict__ dinv,
                                                 unsigned short* __restrict__ g) {
    __shared__ unsigned short lds[128 * WT_PAD];  // 34816 B; reused by epilogue
    int tid = threadIdx.x;
    int wave = tid >> 6, lane = tid & 63;
    int quad = lane >> 4, ln = lane & 15;

    // stage Wt (16384 shorts): thread t copies 64 shorts of row t>>1, half t&1
    {
        int r = tid >> 1, h = tid & 1;
        const int4* src = (const int4*)(Wt + r * 128 + h * 64);
#pragma unroll
        for (int i = 0; i < 8; ++i)
            *(int4*)&lds[r * WT_PAD + h * 64 + i * 8] = src[i];
    }

    int row_base = blockIdx.x * 64 + wave * 16;
    int arow = row_base + ln;  // A-operand: m = lane&15
    bool ok = arow < N_NODES;
    short8 afrag[4];
    if (A_BF16) {
        const unsigned short* A = (const unsigned short*)Ain;
#pragma unroll
        for (int kk = 0; kk < 4; ++kk) {
            short8 v = {};
            if (ok) v = *(const short8*)(A + arow * 128 + kk * 32 + quad * 8);
            afrag[kk] = v;
        }
    } else {
        const float* A = (const float*)Ain;
#pragma unroll
        for (int kk = 0; kk < 4; ++kk) {
            short8 v = {};
            if (ok) {
                const float* p = A + arow * 128 + kk * 32 + quad * 8;
#pragma unroll
                for (int j = 0; j < 8; ++j) v[j] = f2bf(p[j]);
            }
            afrag[kk] = v;
        }
    }
    __syncthreads();

    floatx4 acc[8] = {};
#pragma unroll
    for (int n0 = 0; n0 < 8; ++n0) {
#pragma unroll
        for (int kk = 0; kk < 4; ++kk) {
            // B[k = kk*32+quad*8+j][n = n0*16+ln] = Wt[n][k], 8 contiguous shorts
            short8 b = *(const short8*)&lds[(n0 * 16 + ln) * WT_PAD + kk * 32 + quad * 8];
            acc[n0] = __builtin_amdgcn_mfma_f32_16x16x32_bf16(afrag[kk], b, acc[n0], 0, 0, 0);
        }
    }

    __syncthreads();  // done with Wt; reuse LDS for epilogue transpose
    unsigned short* st = &lds[wave * 16 * WT_PAD];
    float dv[4];
#pragma unroll
    for (int r = 0; r < 4; ++r) {
        int node = row_base + quad * 4 + r;
        dv[r] = (node < N_NODES) ? dinv[node] : 0.f;
    }
#pragma unroll
    for (int n0 = 0; n0 < 8; ++n0)
#pragma unroll
        for (int r = 0; r < 4; ++r)
            st[(quad * 4 + r) * WT_PAD + n0 * 16 + ln] =
                (unsigned short)f2bf(acc[n0][r] * dv[r]);
    __syncthreads();  // publish within block (covers cross-lane within wave too)

#pragma unroll
    for (int i = 0; i < 4; ++i) {
        int row = i * 4 + quad;
        int node = row_base + row;
        short8 v = *(const short8*)&st[row * WT_PAD + ln * 8];
        if (node < N_NODES) *(short8*)(g + node * 128 + ln * 8) = v;
    }
}

// ---------------- aggregation (bf16 gather) ----------------
// out[n] = relu(dinv[n]*(g[n] + sum g[src]) + b); g pre-scaled by dinv[src].
// 256 thr = 8 half-waves; half-wave = one node; lane handles 4 channels (8 B).

template <int MODE>  // 0: bf16 out [N][128]; 1: fp32 split out (x1 | x2)
__global__ __launch_bounds__(256) void aggregate_bf16(const unsigned short* __restrict__ g,
                                                      const float* __restrict__ dinv,
                                                      const int* __restrict__ row_ptr,
                                                      const int* __restrict__ srcs,
                                                      const float* __restrict__ bias,
                                                      void* __restrict__ outp) {
    int sub = threadIdx.x >> 5;
    int n = blockIdx.x * 8 + sub;
    if (n >= N_NODES) return;
    int c2 = threadIdx.x & 31;  // 4-channel group index
    const uint2* grow = (const uint2*)g;  // 32 uint2 per row
    uint2 u = grow[n * 32 + c2];          // self-loop term
    float a0 = bflo(u.x), a1 = bfhi(u.x), a2 = bflo(u.y), a3 = bfhi(u.y);
    float b0 = 0.f, b1 = 0.f, b2_ = 0.f, b3_ = 0.f;
    int e = row_ptr[n], end = row_ptr[n + 1];
    for (; e + 1 < end; e += 2) {
        int s0 = srcs[e], s1 = srcs[e + 1];
        uint2 v0 = grow[s0 * 32 + c2];
        uint2 v1 = grow[s1 * 32 + c2];
        a0 += bflo(v0.x); a1 += bfhi(v0.x); a2 += bflo(v0.y); a3 += bfhi(v0.y);
        b0 += bflo(v1.x); b1 += bfhi(v1.x); b2_ += bflo(v1.y); b3_ += bfhi(v1.y);
    }
    if (e < end) {
        uint2 v = grow[srcs[e] * 32 + c2];
        a0 += bflo(v.x); a1 += bfhi(v.x); a2 += bflo(v.y); a3 += bfhi(v.y);
    }
    a0 += b0; a1 += b1; a2 += b2_; a3 += b3_;
    float d = dinv[n];
    float4 bv = ((const float4*)bias)[c2];
    float o0 = fmaxf(d * a0 + bv.x, 0.f);
    float o1 = fmaxf(d * a1 + bv.y, 0.f);
    float o2 = fmaxf(d * a2 + bv.z, 0.f);
    float o3 = fmaxf(d * a3 + bv.w, 0.f);
    if (MODE == 0) {
        unsigned short* h = (unsigned short*)outp;
        uint2 w;
        w.x = ((unsigned)(unsigned short)f2bf(o0)) | (((unsigned)(unsigned short)f2bf(o1)) << 16);
        w.y = ((unsigned)(unsigned short)f2bf(o2)) | (((unsigned)(unsigned short)f2bf(o3)) << 16);
        ((uint2*)h)[n * 32 + c2] = w;
    } else {
        float* out = (float*)outp;
        float4 o = make_float4(o0, o1, o2, o3);
        if (c2 < 16) ((float4*)out)[n * 16 + c2] = o;                          // x1
        else ((float4*)(out + N_NODES * 64))[n * 16 + (c2 - 16)] = o;          // x2
    }
}

// ---------------- launch ----------------

extern "C" void kernel_launch(void* const* d_in, const int* in_sizes, int n_in,
                              void* d_out, int out_size, void* d_ws, size_t ws_size,
                              hipStream_t stream) {
    const float* x  = (const float*)d_in[0];
    const int*   ei = (const int*)d_in[1];   // [2, E] int32
    const float* W1 = (const float*)d_in[2];
    const float* b1 = (const float*)d_in[3];
    const float* W2 = (const float*)d_in[4];
    const float* b2 = (const float*)d_in[5];
    const float* W3 = (const float*)d_in[6];
    const float* b3 = (const float*)d_in[7];
    float* out = (float*)d_out;

    char* w = (char*)d_ws;
    int*            counts     = (int*)(w + 0);          // 200000 B (reused as cursor)
    int*            row_ptr    = (int*)(w + 204800);     // 200004 B
    float*          dinv       = (float*)(w + 409600);   // 200000 B
    int*            sorted_src = (int*)(w + 614400);     // 3.2 MB
    unsigned short* Wt1        = (unsigned short*)(w + 3814400);  // 32768 B
    unsigned short* Wt23       = (unsigned short*)(w + 3847168);  // 32768 B
    float*          b23        = (float*)(w + 3879936);  // 512 B
    int*            bsum       = (int*)(w + 3880448);    // 392 B
    int*            boff       = (int*)(w + 3880960);    // 392 B
    unsigned short* g1         = (unsigned short*)(w + 4194304);   // 12.8 MB bf16
    unsigned short* hidden     = (unsigned short*)(w + 20971520);  // 12.8 MB bf16

    // CSR build + dinv
    hipMemsetAsync(counts, 0, N_NODES * sizeof(int), stream);
    prep_weights<<<65, 256, 0, stream>>>(W1, W2, W3, b2, b3, Wt1, Wt23, b23);
    count_kernel<<<(N_EDGES + 255) / 256, 256, 0, stream>>>(ei, counts);
    scan_block_kernel<<<SCAN_BLKS, 256, 0, stream>>>(counts, row_ptr, dinv, bsum);
    scan_tops_kernel<<<1, 128, 0, stream>>>(bsum, boff, row_ptr);
    scan_add_kernel<<<SCAN_BLKS, 256, 0, stream>>>(row_ptr, boff, counts);
    scatter_kernel<<<(N_EDGES + 255) / 256, 256, 0, stream>>>(ei, counts, sorted_src);

    const int gemm_blocks = (N_NODES + 63) / 64;  // 782
    const int agg_blocks = (N_NODES + 7) / 8;     // 6250

    // layer 1: g1 = bf16(dinv * (x @ W1)); hidden = bf16(relu(dinv*(self+sum)+b1))
    gemm_mfma<false><<<gemm_blocks, 256, 0, stream>>>(x, Wt1, dinv, g1);
    aggregate_bf16<0><<<agg_blocks, 256, 0, stream>>>(g1, dinv, row_ptr, sorted_src, b1, hidden);

    // layers 2+3 fused: g1 = bf16(dinv * (hidden @ [W2|W3])); out = relu split
    gemm_mfma<true><<<gemm_blocks, 256, 0, stream>>>(hidden, Wt23, dinv, g1);
    aggregate_bf16<1><<<agg_blocks, 256, 0, stream>>>(g1, dinv, row_ptr, sorted_src, b23, out);
}

// Round 4
// 236.810 us; speedup vs baseline: 1.9156x; 1.2112x over previous
//
#include <hip/hip_runtime.h>

#define N_NODES 50000
#define N_EDGES 800000
#define CH 128          // feature width for both GEMM stages (layer2/3 fused)
#define SCAN_BLKS 98    // ceil(50000 / 512)
#define WT_PAD 136      // Wt LDS row stride in shorts (272 B: 16B-aligned, 2-way-free banks)

typedef __attribute__((ext_vector_type(8))) short short8;   // 8 bf16 = one MFMA A/B frag
typedef __attribute__((ext_vector_type(4))) float floatx4;  // MFMA C/D frag

__device__ __forceinline__ short f2bf(float f) {  // RNE float->bf16
    union { float f; unsigned u; } v; v.f = f;
    unsigned r = v.u + 0x7fff + ((v.u >> 16) & 1);
    return (short)(r >> 16);
}
__device__ __forceinline__ float bflo(unsigned u) {  // low bf16 of packed pair -> f32
    union { unsigned u; float f; } v; v.u = u << 16; return v.f;
}
__device__ __forceinline__ float bfhi(unsigned u) {
    union { unsigned u; float f; } v; v.u = u & 0xffff0000u; return v.f;
}

// ---------------- CSR build ----------------

// Fused count + rank: rank[e] = #prior edges with same dst; counts[] ends as degree.
__global__ void rank_kernel(const int* __restrict__ ei, int* __restrict__ counts,
                            int* __restrict__ rank) {
    int e = blockIdx.x * blockDim.x + threadIdx.x;
    if (e < N_EDGES) rank[e] = atomicAdd(&counts[ei[N_EDGES + e]], 1);
}

__global__ __launch_bounds__(256) void scan_block_kernel(const int* __restrict__ counts,
                                                         int* __restrict__ row_ptr,
                                                         float* __restrict__ dinv,
                                                         int* __restrict__ bsum) {
    __shared__ int s[256];
    int tid = threadIdx.x;
    int base = blockIdx.x * 512;
    int i0 = base + 2 * tid, i1 = i0 + 1;
    int v0 = (i0 < N_NODES) ? counts[i0] : 0;
    int v1 = (i1 < N_NODES) ? counts[i1] : 0;
    if (i0 < N_NODES) dinv[i0] = rsqrtf((float)(v0 + 1));  // +1 self-loop
    if (i1 < N_NODES) dinv[i1] = rsqrtf((float)(v1 + 1));
    int t = v0 + v1;
    s[tid] = t;
    __syncthreads();
    for (int off = 1; off < 256; off <<= 1) {
        int tmp = (tid >= off) ? s[tid - off] : 0;
        __syncthreads();
        s[tid] += tmp;
        __syncthreads();
    }
    int pre = s[tid] - t;
    if (i0 < N_NODES) row_ptr[i0] = pre;
    if (i1 < N_NODES) row_ptr[i1] = pre + v0;
    if (tid == 255) bsum[blockIdx.x] = s[255];
}

__global__ __launch_bounds__(128) void scan_tops_kernel(const int* __restrict__ bsum,
                                                        int* __restrict__ boff,
                                                        int* __restrict__ row_ptr) {
    __shared__ int s[128];
    int tid = threadIdx.x;
    int v = (tid < SCAN_BLKS) ? bsum[tid] : 0;
    s[tid] = v;
    __syncthreads();
    for (int off = 1; off < 128; off <<= 1) {
        int tmp = (tid >= off) ? s[tid - off] : 0;
        __syncthreads();
        s[tid] += tmp;
        __syncthreads();
    }
    if (tid < SCAN_BLKS) boff[tid] = s[tid] - v;
    if (tid == 127) row_ptr[N_NODES] = s[127];
}

__global__ __launch_bounds__(256) void scan_add_kernel(int* __restrict__ row_ptr,
                                                       const int* __restrict__ boff) {
    int base = blockIdx.x * 512;
    int off = boff[blockIdx.x];
    for (int i = base + threadIdx.x; i < base + 512; i += 256)
        if (i < N_NODES) row_ptr[i] += off;
}

// Atomic-free scatter: position is fully determined by row_ptr[dst] + rank[e].
__global__ void scatter_plain(const int* __restrict__ ei, const int* __restrict__ row_ptr,
                              const int* __restrict__ rank, int* __restrict__ sorted_src) {
    int e = blockIdx.x * blockDim.x + threadIdx.x;
    if (e < N_EDGES) {
        int dst = ei[N_EDGES + e];
        sorted_src[row_ptr[dst] + rank[e]] = ei[e];
    }
}

// ---------------- weight prep: transpose to [n][k] + bf16 + fuse W2|W3 ----------------

__global__ void prep_weights(const float* __restrict__ W1, const float* __restrict__ W2,
                             const float* __restrict__ W3, const float* __restrict__ b2,
                             const float* __restrict__ b3, unsigned short* __restrict__ Wt1,
                             unsigned short* __restrict__ Wt23, float* __restrict__ b23) {
    int i = blockIdx.x * blockDim.x + threadIdx.x;
    if (i < 128 * 128) {
        int n = i >> 7, k = i & 127;
        Wt1[i] = (unsigned short)f2bf(W1[k * 128 + n]);
        float w = (n < 64) ? W2[k * 64 + n] : W3[k * 64 + (n - 64)];
        Wt23[i] = (unsigned short)f2bf(w);
    } else if (i < 128 * 128 + 128) {
        int k2 = i - 128 * 128;
        b23[k2] = (k2 < 64) ? b2[k2] : b3[k2 - 64];
    }
}

// ---------------- MFMA GEMM: g[n][ch] = bf16( dinv[n] * sum_c A[n][c]*W[c][ch] ) -------

template <bool A_BF16>
__global__ __launch_bounds__(256) void gemm_mfma(const void* __restrict__ Ain,
                                                 const unsigned short* __restrict__ Wt,
                                                 const float* __restrict__ dinv,
                                                 unsigned short* __restrict__ g) {
    __shared__ unsigned short lds[128 * WT_PAD];  // 34816 B; reused by epilogue
    int tid = threadIdx.x;
    int wave = tid >> 6, lane = tid & 63;
    int quad = lane >> 4, ln = lane & 15;

    // stage Wt (16384 shorts): thread t copies 64 shorts of row t>>1, half t&1
    {
        int r = tid >> 1, h = tid & 1;
        const int4* src = (const int4*)(Wt + r * 128 + h * 64);
#pragma unroll
        for (int i = 0; i < 8; ++i)
            *(int4*)&lds[r * WT_PAD + h * 64 + i * 8] = src[i];
    }

    int row_base = blockIdx.x * 64 + wave * 16;
    int arow = row_base + ln;  // A-operand: m = lane&15
    bool ok = arow < N_NODES;
    short8 afrag[4];
    if (A_BF16) {
        const unsigned short* A = (const unsigned short*)Ain;
#pragma unroll
        for (int kk = 0; kk < 4; ++kk) {
            short8 v = {};
            if (ok) v = *(const short8*)(A + arow * 128 + kk * 32 + quad * 8);
            afrag[kk] = v;
        }
    } else {
        const float* A = (const float*)Ain;
#pragma unroll
        for (int kk = 0; kk < 4; ++kk) {
            short8 v = {};
            if (ok) {
                const float* p = A + arow * 128 + kk * 32 + quad * 8;
#pragma unroll
                for (int j = 0; j < 8; ++j) v[j] = f2bf(p[j]);
            }
            afrag[kk] = v;
        }
    }
    __syncthreads();

    floatx4 acc[8] = {};
#pragma unroll
    for (int n0 = 0; n0 < 8; ++n0) {
#pragma unroll
        for (int kk = 0; kk < 4; ++kk) {
            short8 b = *(const short8*)&lds[(n0 * 16 + ln) * WT_PAD + kk * 32 + quad * 8];
            acc[n0] = __builtin_amdgcn_mfma_f32_16x16x32_bf16(afrag[kk], b, acc[n0], 0, 0, 0);
        }
    }

    __syncthreads();  // done with Wt; reuse LDS for epilogue transpose
    unsigned short* st = &lds[wave * 16 * WT_PAD];
    float dv[4];
#pragma unroll
    for (int r = 0; r < 4; ++r) {
        int node = row_base + quad * 4 + r;
        dv[r] = (node < N_NODES) ? dinv[node] : 0.f;
    }
#pragma unroll
    for (int n0 = 0; n0 < 8; ++n0)
#pragma unroll
        for (int r = 0; r < 4; ++r)
            st[(quad * 4 + r) * WT_PAD + n0 * 16 + ln] =
                (unsigned short)f2bf(acc[n0][r] * dv[r]);
    __syncthreads();

#pragma unroll
    for (int i = 0; i < 4; ++i) {
        int row = i * 4 + quad;
        int node = row_base + row;
        short8 v = *(const short8*)&st[row * WT_PAD + ln * 8];
        if (node < N_NODES) *(short8*)(g + node * 128 + ln * 8) = v;
    }
}

// ---------------- aggregation (bf16 gather, 4-edge unroll) ----------------

template <int MODE>  // 0: bf16 out [N][128]; 1: fp32 split out (x1 | x2)
__global__ __launch_bounds__(256) void aggregate_bf16(const unsigned short* __restrict__ g,
                                                      const float* __restrict__ dinv,
                                                      const int* __restrict__ row_ptr,
                                                      const int* __restrict__ srcs,
                                                      const float* __restrict__ bias,
                                                      void* __restrict__ outp) {
    int sub = threadIdx.x >> 5;
    int n = blockIdx.x * 8 + sub;
    if (n >= N_NODES) return;
    int c2 = threadIdx.x & 31;  // 4-channel group index
    const uint2* grow = (const uint2*)g;  // 32 uint2 per row
    uint2 u = grow[n * 32 + c2];          // self-loop term
    float a0 = bflo(u.x), a1 = bfhi(u.x), a2 = bflo(u.y), a3 = bfhi(u.y);
    float b0 = 0.f, b1 = 0.f, b2_ = 0.f, b3_ = 0.f;
    int e = row_ptr[n], end = row_ptr[n + 1];
    for (; e + 3 < end; e += 4) {
        int s0 = srcs[e], s1 = srcs[e + 1], s2 = srcs[e + 2], s3 = srcs[e + 3];
        uint2 v0 = grow[s0 * 32 + c2];
        uint2 v1 = grow[s1 * 32 + c2];
        uint2 v2 = grow[s2 * 32 + c2];
        uint2 v3 = grow[s3 * 32 + c2];
        a0 += bflo(v0.x); a1 += bfhi(v0.x); a2 += bflo(v0.y); a3 += bfhi(v0.y);
        b0 += bflo(v1.x); b1 += bfhi(v1.x); b2_ += bflo(v1.y); b3_ += bfhi(v1.y);
        a0 += bflo(v2.x); a1 += bfhi(v2.x); a2 += bflo(v2.y); a3 += bfhi(v2.y);
        b0 += bflo(v3.x); b1 += bfhi(v3.x); b2_ += bflo(v3.y); b3_ += bfhi(v3.y);
    }
    for (; e < end; ++e) {
        uint2 v = grow[srcs[e] * 32 + c2];
        a0 += bflo(v.x); a1 += bfhi(v.x); a2 += bflo(v.y); a3 += bfhi(v.y);
    }
    a0 += b0; a1 += b1; a2 += b2_; a3 += b3_;
    float d = dinv[n];
    float4 bv = ((const float4*)bias)[c2];
    float o0 = fmaxf(d * a0 + bv.x, 0.f);
    float o1 = fmaxf(d * a1 + bv.y, 0.f);
    float o2 = fmaxf(d * a2 + bv.z, 0.f);
    float o3 = fmaxf(d * a3 + bv.w, 0.f);
    if (MODE == 0) {
        unsigned short* h = (unsigned short*)outp;
        uint2 w;
        w.x = ((unsigned)(unsigned short)f2bf(o0)) | (((unsigned)(unsigned short)f2bf(o1)) << 16);
        w.y = ((unsigned)(unsigned short)f2bf(o2)) | (((unsigned)(unsigned short)f2bf(o3)) << 16);
        ((uint2*)h)[n * 32 + c2] = w;
    } else {
        float* out = (float*)outp;
        float4 o = make_float4(o0, o1, o2, o3);
        if (c2 < 16) ((float4*)out)[n * 16 + c2] = o;                          // x1
        else ((float4*)(out + N_NODES * 64))[n * 16 + (c2 - 16)] = o;          // x2
    }
}

// ---------------- launch ----------------

extern "C" void kernel_launch(void* const* d_in, const int* in_sizes, int n_in,
                              void* d_out, int out_size, void* d_ws, size_t ws_size,
                              hipStream_t stream) {
    const float* x  = (const float*)d_in[0];
    const int*   ei = (const int*)d_in[1];   // [2, E] int32
    const float* W1 = (const float*)d_in[2];
    const float* b1 = (const float*)d_in[3];
    const float* W2 = (const float*)d_in[4];
    const float* b2 = (const float*)d_in[5];
    const float* W3 = (const float*)d_in[6];
    const float* b3 = (const float*)d_in[7];
    float* out = (float*)d_out;

    char* w = (char*)d_ws;
    int*            counts     = (int*)(w + 0);                   // 200000 B
    int*            row_ptr    = (int*)(w + 204800);              // 200004 B
    float*          dinv       = (float*)(w + 409600);            // 200000 B
    int*            rank       = (int*)(w + 614400);              // 3.2 MB
    int*            sorted_src = (int*)(w + 3814400);             // 3.2 MB
    unsigned short* Wt1        = (unsigned short*)(w + 7014400);  // 32768 B
    unsigned short* Wt23       = (unsigned short*)(w + 7047168);  // 32768 B
    float*          b23        = (float*)(w + 7079936);           // 512 B
    int*            bsum       = (int*)(w + 7080448);             // 512 B
    int*            boff       = (int*)(w + 7080960);             // 512 B
    unsigned short* g1         = (unsigned short*)(w + 8388608);  // 12.8 MB bf16
    unsigned short* hidden     = (unsigned short*)(w + 25165824); // 12.8 MB bf16

    // CSR build + dinv (single atomic pass; scatter is atomic-free)
    hipMemsetAsync(counts, 0, N_NODES * sizeof(int), stream);
    prep_weights<<<65, 256, 0, stream>>>(W1, W2, W3, b2, b3, Wt1, Wt23, b23);
    rank_kernel<<<(N_EDGES + 255) / 256, 256, 0, stream>>>(ei, counts, rank);
    scan_block_kernel<<<SCAN_BLKS, 256, 0, stream>>>(counts, row_ptr, dinv, bsum);
    scan_tops_kernel<<<1, 128, 0, stream>>>(bsum, boff, row_ptr);
    scan_add_kernel<<<SCAN_BLKS, 256, 0, stream>>>(row_ptr, boff);
    scatter_plain<<<(N_EDGES + 255) / 256, 256, 0, stream>>>(ei, row_ptr, rank, sorted_src);

    const int gemm_blocks = (N_NODES + 63) / 64;  // 782
    const int agg_blocks = (N_NODES + 7) / 8;     // 6250

    // layer 1: g1 = bf16(dinv * (x @ W1)); hidden = bf16(relu(dinv*(self+sum)+b1))
    gemm_mfma<false><<<gemm_blocks, 256, 0, stream>>>(x, Wt1, dinv, g1);
    aggregate_bf16<0><<<agg_blocks, 256, 0, stream>>>(g1, dinv, row_ptr, sorted_src, b1, hidden);

    // layers 2+3 fused: g1 = bf16(dinv * (hidden @ [W2|W3])); out = relu split
    gemm_mfma<true><<<gemm_blocks, 256, 0, stream>>>(hidden, Wt23, dinv, g1);
    aggregate_bf16<1><<<agg_blocks, 256, 0, stream>>>(g1, dinv, row_ptr, sorted_src, b23, out);
}

// Round 5
// 225.948 us; speedup vs baseline: 2.0077x; 1.0481x over previous
//
#include <hip/hip_runtime.h>

#define N_NODES 50000
#define N_EDGES 800000
#define CH 128          // feature width for both GEMM stages (layer2/3 fused)
#define SCAN_BLKS 98    // ceil(50000 / 512)
#define WT_PAD 136      // Wt LDS row stride in shorts (272 B: 16B-aligned, 2-way-free banks)
#define DUMMY N_NODES   // g row 50000 is zeroed; CSR padding points here

typedef __attribute__((ext_vector_type(8))) short short8;   // 8 bf16 = one MFMA A/B frag
typedef __attribute__((ext_vector_type(4))) float floatx4;  // MFMA C/D frag

__device__ __forceinline__ short f2bf(float f) {  // RNE float->bf16
    union { float f; unsigned u; } v; v.f = f;
    unsigned r = v.u + 0x7fff + ((v.u >> 16) & 1);
    return (short)(r >> 16);
}
__device__ __forceinline__ float bflo(unsigned u) {
    union { unsigned u; float f; } v; v.u = u << 16; return v.f;
}
__device__ __forceinline__ float bfhi(unsigned u) {
    union { unsigned u; float f; } v; v.u = u & 0xffff0000u; return v.f;
}

// ---------------- prep: weights transpose/fuse + zero counts + zero dummy g row -------

__global__ __launch_bounds__(256) void prep_kernel(const float* __restrict__ W1,
                                                   const float* __restrict__ W2,
                                                   const float* __restrict__ W3,
                                                   const float* __restrict__ b2,
                                                   const float* __restrict__ b3,
                                                   unsigned short* __restrict__ Wt1,
                                                   unsigned short* __restrict__ Wt23,
                                                   float* __restrict__ b23,
                                                   int* __restrict__ counts,
                                                   unsigned int* __restrict__ gdummy) {
    int i = blockIdx.x * blockDim.x + threadIdx.x;   // 66*256 = 16896 threads
    if (i < 128 * 128) {
        int n = i >> 7, k = i & 127;
        Wt1[i] = (unsigned short)f2bf(W1[k * 128 + n]);
        float w = (n < 64) ? W2[k * 64 + n] : W3[k * 64 + (n - 64)];
        Wt23[i] = (unsigned short)f2bf(w);
    } else if (i < 128 * 128 + 128) {
        int k2 = i - 128 * 128;
        b23[k2] = (k2 < 64) ? b2[k2] : b3[k2 - 64];
    } else if (i < 128 * 128 + 192) {
        gdummy[i - (128 * 128 + 128)] = 0;           // 64 uints = 128 bf16 zeros
    }
    for (int j = i; j < N_NODES; j += 66 * 256) counts[j] = 0;
}

// ---------------- CSR build ----------------

// Fused count + rank: rank[e] = #prior edges with same dst; counts[] ends as degree.
__global__ void rank_kernel(const int* __restrict__ ei, int* __restrict__ counts,
                            int* __restrict__ rank) {
    int e = blockIdx.x * blockDim.x + threadIdx.x;
    if (e < N_EDGES) rank[e] = atomicAdd(&counts[ei[N_EDGES + e]], 1);
}

// Per-block exclusive scan of PADDED degrees (ceil4) + dinv from true degree.
__global__ __launch_bounds__(256) void scan_block_kernel(const int* __restrict__ counts,
                                                         int* __restrict__ row_ptr,
                                                         float* __restrict__ dinv,
                                                         int* __restrict__ bsum) {
    __shared__ int s[256];
    int tid = threadIdx.x;
    int base = blockIdx.x * 512;
    int i0 = base + 2 * tid, i1 = i0 + 1;
    int v0 = (i0 < N_NODES) ? counts[i0] : 0;
    int v1 = (i1 < N_NODES) ? counts[i1] : 0;
    if (i0 < N_NODES) dinv[i0] = rsqrtf((float)(v0 + 1));  // +1 self-loop
    if (i1 < N_NODES) dinv[i1] = rsqrtf((float)(v1 + 1));
    int p0 = (v0 + 3) & ~3, p1 = (v1 + 3) & ~3;            // 4-aligned rows
    int t = p0 + p1;
    s[tid] = t;
    __syncthreads();
    for (int off = 1; off < 256; off <<= 1) {
        int tmp = (tid >= off) ? s[tid - off] : 0;
        __syncthreads();
        s[tid] += tmp;
        __syncthreads();
    }
    int pre = s[tid] - t;
    if (i0 < N_NODES) row_ptr[i0] = pre;
    if (i1 < N_NODES) row_ptr[i1] = pre + p0;
    if (tid == 255) bsum[blockIdx.x] = s[255];
}

// Each block redundantly scans the 98 block sums (LDS), adds its offset to its
// 512 row_ptr entries, and fills the CSR padding slots with DUMMY.
__global__ __launch_bounds__(256) void scan_fix_kernel(int* __restrict__ row_ptr,
                                                       const int* __restrict__ bsum,
                                                       const int* __restrict__ degs,
                                                       int* __restrict__ sorted_src) {
    __shared__ int s[128];
    int tid = threadIdx.x;
    if (tid < 128) s[tid] = (tid < SCAN_BLKS) ? bsum[tid] : 0;
    __syncthreads();
    for (int off = 1; off < 128; off <<= 1) {
        int t = (tid < 128 && tid >= off) ? s[tid - off] : 0;
        __syncthreads();
        if (tid < 128) s[tid] += t;
        __syncthreads();
    }
    int blockoff = (blockIdx.x == 0) ? 0 : s[blockIdx.x - 1];
    int base = blockIdx.x * 512;
    for (int i = base + tid; i < base + 512; i += 256) {
        if (i < N_NODES) {
            int v = row_ptr[i] + blockoff;
            row_ptr[i] = v;
            int d = degs[i];
            int pc = (d + 3) & ~3;
            for (int p = v + d; p < v + pc; ++p) sorted_src[p] = DUMMY;
        }
    }
}

// Atomic-free scatter: position fully determined by row_ptr[dst] + rank[e].
__global__ void scatter_plain(const int* __restrict__ ei, const int* __restrict__ row_ptr,
                              const int* __restrict__ rank, int* __restrict__ sorted_src) {
    int e = blockIdx.x * blockDim.x + threadIdx.x;
    if (e < N_EDGES) {
        int dst = ei[N_EDGES + e];
        sorted_src[row_ptr[dst] + rank[e]] = ei[e];
    }
}

// ---------------- MFMA GEMM: g[n][ch] = bf16( dinv[n] * sum_c A[n][c]*W[c][ch] ) -------

template <bool A_BF16>
__global__ __launch_bounds__(256) void gemm_mfma(const void* __restrict__ Ain,
                                                 const unsigned short* __restrict__ Wt,
                                                 const float* __restrict__ dinv,
                                                 unsigned short* __restrict__ g) {
    __shared__ unsigned short lds[128 * WT_PAD];  // 34816 B; reused by epilogue
    int tid = threadIdx.x;
    int wave = tid >> 6, lane = tid & 63;
    int quad = lane >> 4, ln = lane & 15;

    {   // stage Wt (16384 shorts): thread t copies 64 shorts of row t>>1, half t&1
        int r = tid >> 1, h = tid & 1;
        const int4* src = (const int4*)(Wt + r * 128 + h * 64);
#pragma unroll
        for (int i = 0; i < 8; ++i)
            *(int4*)&lds[r * WT_PAD + h * 64 + i * 8] = src[i];
    }

    int row_base = blockIdx.x * 64 + wave * 16;
    int arow = row_base + ln;  // A-operand: m = lane&15
    bool ok = arow < N_NODES;
    short8 afrag[4];
    if (A_BF16) {
        const unsigned short* A = (const unsigned short*)Ain;
#pragma unroll
        for (int kk = 0; kk < 4; ++kk) {
            short8 v = {};
            if (ok) v = *(const short8*)(A + arow * 128 + kk * 32 + quad * 8);
            afrag[kk] = v;
        }
    } else {
        const float* A = (const float*)Ain;
#pragma unroll
        for (int kk = 0; kk < 4; ++kk) {
            short8 v = {};
            if (ok) {
                const float* p = A + arow * 128 + kk * 32 + quad * 8;
#pragma unroll
                for (int j = 0; j < 8; ++j) v[j] = f2bf(p[j]);
            }
            afrag[kk] = v;
        }
    }
    __syncthreads();

    floatx4 acc[8] = {};
#pragma unroll
    for (int n0 = 0; n0 < 8; ++n0) {
#pragma unroll
        for (int kk = 0; kk < 4; ++kk) {
            short8 b = *(const short8*)&lds[(n0 * 16 + ln) * WT_PAD + kk * 32 + quad * 8];
            acc[n0] = __builtin_amdgcn_mfma_f32_16x16x32_bf16(afrag[kk], b, acc[n0], 0, 0, 0);
        }
    }

    __syncthreads();  // done with Wt; reuse LDS for epilogue transpose
    unsigned short* st = &lds[wave * 16 * WT_PAD];
    float dv[4];
#pragma unroll
    for (int r = 0; r < 4; ++r) {
        int node = row_base + quad * 4 + r;
        dv[r] = (node < N_NODES) ? dinv[node] : 0.f;
    }
#pragma unroll
    for (int n0 = 0; n0 < 8; ++n0)
#pragma unroll
        for (int r = 0; r < 4; ++r)
            st[(quad * 4 + r) * WT_PAD + n0 * 16 + ln] =
                (unsigned short)f2bf(acc[n0][r] * dv[r]);
    __syncthreads();

#pragma unroll
    for (int i = 0; i < 4; ++i) {
        int row = i * 4 + quad;
        int node = row_base + row;
        short8 v = *(const short8*)&st[row * WT_PAD + ln * 8];
        if (node < N_NODES) *(short8*)(g + node * 128 + ln * 8) = v;
    }
}

// ---------------- aggregation (bf16 gather, int4 srcs, 8 gathers in flight) -----------
// Rows are 4-padded with DUMMY (zero row) -> no tail, aligned int4 index loads.

template <int MODE>  // 0: bf16 out [N][128]; 1: fp32 split out (x1 | x2)
__global__ __launch_bounds__(256) void aggregate_bf16(const unsigned short* __restrict__ g,
                                                      const float* __restrict__ dinv,
                                                      const int* __restrict__ row_ptr,
                                                      const int* __restrict__ degs,
                                                      const int* __restrict__ srcs,
                                                      const float* __restrict__ bias,
                                                      void* __restrict__ outp) {
    int sub = threadIdx.x >> 5;
    int n = blockIdx.x * 8 + sub;
    if (n >= N_NODES) return;
    int c2 = threadIdx.x & 31;  // 4-channel group index
    const uint2* grow = (const uint2*)g;  // 32 uint2 per row
    uint2 u = grow[n * 32 + c2];          // self-loop term
    float a0 = bflo(u.x), a1 = bfhi(u.x), a2 = bflo(u.y), a3 = bfhi(u.y);
    float b0 = 0.f, b1 = 0.f, b2_ = 0.f, b3_ = 0.f;
    int beg = row_ptr[n];
    int pend = beg + ((degs[n] + 3) & ~3);
    int e = beg;
    for (; e + 8 <= pend; e += 8) {
        int4 sa = *(const int4*)&srcs[e];
        int4 sb = *(const int4*)&srcs[e + 4];
        uint2 v0 = grow[sa.x * 32 + c2];
        uint2 v1 = grow[sa.y * 32 + c2];
        uint2 v2 = grow[sa.z * 32 + c2];
        uint2 v3 = grow[sa.w * 32 + c2];
        uint2 v4 = grow[sb.x * 32 + c2];
        uint2 v5 = grow[sb.y * 32 + c2];
        uint2 v6 = grow[sb.z * 32 + c2];
        uint2 v7 = grow[sb.w * 32 + c2];
        a0 += bflo(v0.x); a1 += bfhi(v0.x); a2 += bflo(v0.y); a3 += bfhi(v0.y);
        b0 += bflo(v1.x); b1 += bfhi(v1.x); b2_ += bflo(v1.y); b3_ += bfhi(v1.y);
        a0 += bflo(v2.x); a1 += bfhi(v2.x); a2 += bflo(v2.y); a3 += bfhi(v2.y);
        b0 += bflo(v3.x); b1 += bfhi(v3.x); b2_ += bflo(v3.y); b3_ += bfhi(v3.y);
        a0 += bflo(v4.x); a1 += bfhi(v4.x); a2 += bflo(v4.y); a3 += bfhi(v4.y);
        b0 += bflo(v5.x); b1 += bfhi(v5.x); b2_ += bflo(v5.y); b3_ += bfhi(v5.y);
        a0 += bflo(v6.x); a1 += bfhi(v6.x); a2 += bflo(v6.y); a3 += bfhi(v6.y);
        b0 += bflo(v7.x); b1 += bfhi(v7.x); b2_ += bflo(v7.y); b3_ += bfhi(v7.y);
    }
    if (e < pend) {  // exactly one 4-wide chunk (pend-beg is a multiple of 4)
        int4 sa = *(const int4*)&srcs[e];
        uint2 v0 = grow[sa.x * 32 + c2];
        uint2 v1 = grow[sa.y * 32 + c2];
        uint2 v2 = grow[sa.z * 32 + c2];
        uint2 v3 = grow[sa.w * 32 + c2];
        a0 += bflo(v0.x); a1 += bfhi(v0.x); a2 += bflo(v0.y); a3 += bfhi(v0.y);
        b0 += bflo(v1.x); b1 += bfhi(v1.x); b2_ += bflo(v1.y); b3_ += bfhi(v1.y);
        a0 += bflo(v2.x); a1 += bfhi(v2.x); a2 += bflo(v2.y); a3 += bfhi(v2.y);
        b0 += bflo(v3.x); b1 += bfhi(v3.x); b2_ += bflo(v3.y); b3_ += bfhi(v3.y);
    }
    a0 += b0; a1 += b1; a2 += b2_; a3 += b3_;
    float d = dinv[n];
    float4 bv = ((const float4*)bias)[c2];
    float o0 = fmaxf(d * a0 + bv.x, 0.f);
    float o1 = fmaxf(d * a1 + bv.y, 0.f);
    float o2 = fmaxf(d * a2 + bv.z, 0.f);
    float o3 = fmaxf(d * a3 + bv.w, 0.f);
    if (MODE == 0) {
        unsigned short* h = (unsigned short*)outp;
        uint2 w;
        w.x = ((unsigned)(unsigned short)f2bf(o0)) | (((unsigned)(unsigned short)f2bf(o1)) << 16);
        w.y = ((unsigned)(unsigned short)f2bf(o2)) | (((unsigned)(unsigned short)f2bf(o3)) << 16);
        ((uint2*)h)[n * 32 + c2] = w;
    } else {
        float* out = (float*)outp;
        float4 o = make_float4(o0, o1, o2, o3);
        if (c2 < 16) ((float4*)out)[n * 16 + c2] = o;                          // x1
        else ((float4*)(out + N_NODES * 64))[n * 16 + (c2 - 16)] = o;          // x2
    }
}

// ---------------- launch ----------------

extern "C" void kernel_launch(void* const* d_in, const int* in_sizes, int n_in,
                              void* d_out, int out_size, void* d_ws, size_t ws_size,
                              hipStream_t stream) {
    const float* x  = (const float*)d_in[0];
    const int*   ei = (const int*)d_in[1];   // [2, E] int32
    const float* W1 = (const float*)d_in[2];
    const float* b1 = (const float*)d_in[3];
    const float* W2 = (const float*)d_in[4];
    const float* b2 = (const float*)d_in[5];
    const float* W3 = (const float*)d_in[6];
    const float* b3 = (const float*)d_in[7];
    float* out = (float*)d_out;

    char* w = (char*)d_ws;
    int*            counts     = (int*)(w + 0);                   // 200000 B (ends as degree)
    int*            row_ptr    = (int*)(w + 204800);              // 200000 B (padded CSR)
    float*          dinv       = (float*)(w + 409600);            // 200000 B
    int*            rank       = (int*)(w + 614400);              // 3.2 MB
    int*            sorted_src = (int*)(w + 3814400);             // 3.8 MB (padded)
    unsigned short* Wt1        = (unsigned short*)(w + 7614400);  // 32768 B
    unsigned short* Wt23       = (unsigned short*)(w + 7647168);  // 32768 B
    float*          b23        = (float*)(w + 7679936);           // 512 B
    int*            bsum       = (int*)(w + 7680448);             // 512 B
    unsigned short* g1         = (unsigned short*)(w + 8388608);  // 12.8 MB + dummy row
    unsigned short* hidden     = (unsigned short*)(w + 22020096); // 12.8 MB

    // prep (weights + zero counts + zero dummy g row) then CSR build
    prep_kernel<<<66, 256, 0, stream>>>(W1, W2, W3, b2, b3, Wt1, Wt23, b23, counts,
                                        (unsigned int*)(g1 + N_NODES * 128));
    rank_kernel<<<(N_EDGES + 255) / 256, 256, 0, stream>>>(ei, counts, rank);
    scan_block_kernel<<<SCAN_BLKS, 256, 0, stream>>>(counts, row_ptr, dinv, bsum);
    scan_fix_kernel<<<SCAN_BLKS, 256, 0, stream>>>(row_ptr, bsum, counts, sorted_src);
    scatter_plain<<<(N_EDGES + 255) / 256, 256, 0, stream>>>(ei, row_ptr, rank, sorted_src);

    const int gemm_blocks = (N_NODES + 63) / 64;  // 782
    const int agg_blocks = (N_NODES + 7) / 8;     // 6250

    // layer 1: g1 = bf16(dinv * (x @ W1)); hidden = bf16(relu(dinv*(self+sum)+b1))
    gemm_mfma<false><<<gemm_blocks, 256, 0, stream>>>(x, Wt1, dinv, g1);
    aggregate_bf16<0><<<agg_blocks, 256, 0, stream>>>(g1, dinv, row_ptr, counts, sorted_src, b1, hidden);

    // layers 2+3 fused: g1 = bf16(dinv * (hidden @ [W2|W3])); out = relu split
    gemm_mfma<true><<<gemm_blocks, 256, 0, stream>>>(hidden, Wt23, dinv, g1);
    aggregate_bf16<1><<<agg_blocks, 256, 0, stream>>>(g1, dinv, row_ptr, counts, sorted_src, b23, out);
}